// Round 5
// baseline (821.982 us; speedup 1.0000x reference)
//
#include <hip/hip_runtime.h>
#include <stdint.h>

#define CH 256
#define HWD 56
#define POS 3136
#define BATCH 32

typedef unsigned long long u64;
typedef __attribute__((ext_vector_type(4))) int  i32x4;
typedef __attribute__((ext_vector_type(16))) int i32x16;
typedef __attribute__((ext_vector_type(8))) short short8;

#define GLL16(gsrc, ldst) \
    __builtin_amdgcn_global_load_lds((const __attribute__((address_space(1))) void*)(gsrc), \
                                     (__attribute__((address_space(3))) void*)(ldst), 16, 0, 0)

// ---- pack weights, fragment-ordered: Wb2[tap][cc=c/16][o][c%16] i8 (+1/-1) ----
__global__ void pack_w_kernel(const float* __restrict__ W, char* __restrict__ Wb2){
    int idx = blockIdx.x*256 + threadIdx.x;   // (o*9+tap)*16 + cc
    if (idx >= 256*9*16) return;
    int cc = idx & 15;
    int ot = idx >> 4;
    int o = ot / 9, tap = ot % 9;
    char v16[16];
    #pragma unroll
    for (int j=0;j<16;j++){
        float v = W[(size_t)(o*256 + cc*16 + j)*9 + tap];
        v16[j] = (v >= 0.f) ? 1 : -1;
    }
    *(int4*)(Wb2 + ((size_t)(tap*16 + cc)*256 + o)*16) = *(int4*)v16;
}

// ---- pack input signs, chunk-major padded:
//      SXc[cc 16][b 32][row' 58][slot 58][16B]  (rows 0,57 and slots 0,57 are zero pad)
__global__ __launch_bounds__(256) void pack_x_kernel(const float* __restrict__ x, char* __restrict__ SXc){
    int blk = blockIdx.x;              // b*58 + rp
    int rp = blk % 58, b = blk / 58;
    int t = threadIdx.x;
    if (rp == 0 || rp == 57){          // zero pad rows (all 16 chunks)
        for (int j = t; j < 16*58; j += 256){
            int cc = j / 58, s = j % 58;
            *(int4*)(SXc + ((((size_t)cc*32 + b)*58 + rp)*58 + s)*16) = make_int4(0,0,0,0);
        }
        return;
    }
    int h = rp - 1;
    __shared__ char lds[56][256];
    int wave = t >> 6, l = t & 63;
    // phase 1: read x coalesced along w, write LDS transposed (bank-swizzled)
    for (int i = 0; i < 64; ++i){
        int c = wave*64 + i;
        if (l < 56){
            float v = x[((size_t)(b*256 + c))*POS + h*HWD + l];
            lds[l][c ^ ((l & 31) << 2)] = (v >= 0.f) ? (char)1 : (char)-1;
        }
    }
    __syncthreads();
    // phase 2: emit 16B channel-chunks, contiguous along slot
    if (t < 232){
        int cc4 = t / 58, s = t % 58;
        #pragma unroll
        for (int c4 = 0; c4 < 4; ++c4){
            int cc = c4*4 + cc4;
            int4 val = make_int4(0,0,0,0);
            if (s >= 1 && s <= 56){
                int w = s - 1;
                int swz = (w & 31) << 2;
                val.x = *(const int*)&lds[w][(cc*16 + 0) ^ swz];
                val.y = *(const int*)&lds[w][(cc*16 + 4) ^ swz];
                val.z = *(const int*)&lds[w][(cc*16 + 8) ^ swz];
                val.w = *(const int*)&lds[w][(cc*16 +12) ^ swz];
            }
            *(int4*)(SXc + ((((size_t)cc*32 + b)*58 + rp)*58 + s)*16) = val;
        }
    }
}

// ---- conv: i8 implicit GEMM. Block = (o-half 128, b, output row h). 4 waves 2Mx2N.
// Per-wave 64(o) x 32(col). K-loop kq-major (4 x K64), tap-minor (9), W double-buffered.
__global__ __launch_bounds__(256, 4) void conv_kernel(
        const char* __restrict__ SXc, const char* __restrict__ Wb2,
        short* __restrict__ y16, int* __restrict__ sumI, u64* __restrict__ sumQ){
    __shared__ char BQ[4*3*66*16];      // [kb4][row][slot 66][16B] = 12,672 B
    __shared__ char WL[2][4*128*16];    // [buf][kk][o 128][16B]    = 16,384 B

    int blk = blockIdx.x;
    int gm = blk & 1;
    int bh = blk >> 1;
    int b  = bh / 56;
    int h  = bh % 56;
    int t = threadIdx.x;
    int wave = t >> 6, l = t & 63;
    int wm = wave >> 1, wn = wave & 1;
    int half = l >> 5, l31 = l & 31;

    const char* wsrc = Wb2 + ((size_t)gm*128 + l)*16;   // + (tap*16+cc)*4096

    i32x16 acc[2];
    #pragma unroll
    for (int m=0;m<2;m++)
        #pragma unroll
        for (int r=0;r<16;r++) acc[m][r] = 0;

    #pragma unroll 1
    for (int kq = 0; kq < 4; ++kq){
        __syncthreads();               // all waves done with previous BQ / WL
        // stage BQ(kq): 12 chunks of 58x16B (coalesced 928B each)
        #pragma unroll
        for (int i = 0; i < 3; ++i){
            int u = wave + 4*i;        // 0..11
            int kb4 = u & 3, row = u >> 2;
            const char* g = SXc + ((((size_t)(kq*4+kb4)*32 + b)*58 + h + row)*58 + l)*16;
            if (l < 58)
                GLL16(g, BQ + ((kb4*3 + row)*66)*16);
        }
        // stage W(kq, tap=0) -> buf 0 (8 x 1KB coalesced)
        #pragma unroll
        for (int i = 0; i < 2; ++i){
            int u = wave + 4*i;        // 0..7
            int kk = u & 3, hf = u >> 2;
            GLL16(wsrc + ((size_t)(kq*4 + kk)*256 + hf*64)*16,
                  WL[0] + (kk*128 + hf*64)*16);
        }
        #pragma unroll 1
        for (int tap = 0; tap < 9; ++tap){
            __syncthreads();           // drains this tap's W stage (and BQ at tap==0)
            int dh = tap/3 - 1, dw = tap%3 - 1;
            const char* wbuf = WL[tap & 1];
            // fragment ds_reads FIRST (keep them ahead of the GLL16 issue)
            i32x4 afr[2][2], bfr[2];
            #pragma unroll
            for (int ks = 0; ks < 2; ++ks){
                int kk = 2*ks + half;
                #pragma unroll
                for (int m=0;m<2;m++)
                    afr[ks][m] = *(const i32x4*)(wbuf + (kk*128 + wm*64 + m*32 + l31)*16);
                bfr[ks] = *(const i32x4*)(BQ + ((kk*3 + (dh+1))*66 + 1 + dw + wn*32 + l31)*16);
            }
            if (tap < 8){              // prefetch next tap's W into alternate buffer
                #pragma unroll
                for (int i = 0; i < 2; ++i){
                    int u = wave + 4*i;
                    int kk = u & 3, hf = u >> 2;
                    GLL16(wsrc + ((size_t)((tap+1)*16 + kq*4 + kk)*256 + hf*64)*16,
                          WL[(tap+1) & 1] + (kk*128 + hf*64)*16);
                }
            }
            #pragma unroll
            for (int ks = 0; ks < 2; ++ks){
                acc[0] = __builtin_amdgcn_mfma_i32_32x32x32_i8(afr[ks][0], bfr[ks], acc[0], 0,0,0);
                acc[1] = __builtin_amdgcn_mfma_i32_32x32x32_i8(afr[ks][1], bfr[ks], acc[1], 0,0,0);
            }
        }
    }

    // ---- epilogue: store y (valid cols) + exact integer stats ----
    int n0 = wn*32 + l31;              // output col
    bool vok = (n0 <= 55);
    #pragma unroll
    for (int m=0;m<2;m++){
        #pragma unroll
        for (int reg=0; reg<16; ++reg){
            int o = gm*128 + wm*64 + m*32 + (reg&3) + 8*(reg>>2) + 4*half;
            int v = acc[m][reg];
            if (vok) y16[((size_t)(b*CH + o)*HWD + h)*HWD + n0] = (short)v;
            int s = vok ? v : 0;
            int q = vok ? v*v : 0;     // <= 32*2304^2 = 1.7e8, fits i32
            #pragma unroll
            for (int off=1; off<32; off<<=1){
                s += __shfl_xor(s, off);
                q += __shfl_xor(q, off);
            }
            if (l31 == 0){
                atomicAdd(&sumI[o], s);
                atomicAdd(&sumQ[o], (u64)(unsigned)q);
            }
        }
    }
}

// ---- BN coefficients from exact integer sums ----
__global__ void bn_prep_kernel(const int* __restrict__ sumI, const u64* __restrict__ sumQ,
                               const float* __restrict__ gamma, const float* __restrict__ beta,
                               float* __restrict__ invA, float* __restrict__ shiftA){
    int o = threadIdx.x;
    const double N = (double)(BATCH*POS);
    double mean = (double)sumI[o] / N;
    double msq  = (double)sumQ[o] / N;
    double var  = msq - mean*mean;
    double inv  = (double)gamma[o] / sqrt(var + 1e-5);
    invA[o]   = (float)inv;
    shiftA[o] = (float)((double)beta[o] - mean*inv);
}

// ---- apply: out = y*inv + shift + x ----
__global__ void apply_kernel(const short* __restrict__ y16, const float* __restrict__ x,
                             const float* __restrict__ invA, const float* __restrict__ shiftA,
                             float* __restrict__ out){
    int t = blockIdx.x*blockDim.x + threadIdx.x;
    const int total8 = BATCH*CH*POS/8;
    if (t >= total8) return;
    size_t i = (size_t)t*8;
    int c = (t / (POS/8)) & 255;
    short8 yv = *(const short8*)(y16 + i);
    float4 x0 = *(const float4*)(x + i);
    float4 x1 = *(const float4*)(x + i + 4);
    float iv = invA[c], sh = shiftA[c];
    float4 o0, o1;
    o0.x = fmaf((float)yv[0], iv, sh) + x0.x;
    o0.y = fmaf((float)yv[1], iv, sh) + x0.y;
    o0.z = fmaf((float)yv[2], iv, sh) + x0.z;
    o0.w = fmaf((float)yv[3], iv, sh) + x0.w;
    o1.x = fmaf((float)yv[4], iv, sh) + x1.x;
    o1.y = fmaf((float)yv[5], iv, sh) + x1.y;
    o1.z = fmaf((float)yv[6], iv, sh) + x1.z;
    o1.w = fmaf((float)yv[7], iv, sh) + x1.w;
    *(float4*)(out + i)     = o0;
    *(float4*)(out + i + 4) = o1;
}

extern "C" void kernel_launch(void* const* d_in, const int* in_sizes, int n_in,
                              void* d_out, int out_size, void* d_ws, size_t ws_size,
                              hipStream_t stream) {
    const float* x     = (const float*)d_in[0];
    const float* W     = (const float*)d_in[1];
    const float* gamma = (const float*)d_in[2];
    const float* beta  = (const float*)d_in[3];
    float* out = (float*)d_out;

    // ws layout: y16 (51,380,224) | sumI (1024) | sumQ (2048) | invA | shiftA
    char* ws = (char*)d_ws;
    short* y16   = (short*)ws;
    int*   sumI  = (int*)(ws + 51380224);
    u64*   sumQ  = (u64*)(ws + 51381248);
    float* invA  = (float*)(ws + 51383296);
    float* shiftA= (float*)(ws + 51384320);

    // d_out doubles as scratch for SXc (27.6MB) + Wb2 (0.59MB); both dead
    // before apply_kernel overwrites d_out with the final result.
    char* ob  = (char*)d_out;
    char* SXc = ob;                      // 16*32*58*58*16 = 27,557,888
    char* Wb2 = ob + 28000000;           // 589,824

    hipMemsetAsync(sumI, 0, 3072, stream);

    pack_w_kernel<<<144, 256, 0, stream>>>(W, Wb2);
    pack_x_kernel<<<BATCH*58, 256, 0, stream>>>(x, SXc);
    conv_kernel<<<2*BATCH*HWD, 256, 0, stream>>>(SXc, Wb2, y16, sumI, sumQ);
    bn_prep_kernel<<<1, 256, 0, stream>>>(sumI, sumQ, gamma, beta, invA, shiftA);
    apply_kernel<<<(BATCH*CH*POS/8 + 255)/256, 256, 0, stream>>>(y16, x, invA, shiftA, out);
}

// Round 7
// 414.351 us; speedup vs baseline: 1.9838x; 1.9838x over previous
//
#include <hip/hip_runtime.h>
#include <stdint.h>

#define CH 256
#define HWD 56
#define POS 3136
#define BATCH 32
#define PADW 58
#define PADP (PADW*PADW)     // 3364

typedef unsigned long long u64;
typedef __attribute__((ext_vector_type(8))) short short8;

// ---- pack weights: wbit8[og 32][tap 9][oo 8][g 4] u64 + ctap[o 256][tap 9] ----
__global__ void pack_w_kernel(const float* __restrict__ W, u64* __restrict__ wbit8,
                              int* __restrict__ ctap){
    int idx = blockIdx.x*256 + threadIdx.x;   // o*9 + tap
    if (idx >= CH*9) return;
    int o = idx / 9, tap = idx % 9;
    int kh = tap/3, kw = tap%3;
    int og = o >> 3, oo = o & 7;
    int totpop = 0;
    for (int g=0; g<4; g++){
        u64 bits = 0;
        for (int j=0; j<64; j++){
            float v = W[((size_t)(o*CH + g*64 + j)*3 + kh)*3 + kw];
            bits |= (u64)(v >= 0.f) << j;
        }
        wbit8[((size_t)(og*9 + tap)*8 + oo)*4 + g] = bits;
        totpop += __builtin_popcountll(bits);
    }
    ctap[o*9 + tap] = 256 - 2*totpop;   // contribution of a zero-padded tap
}

// ---- pack input signs into zero-padded 58x58 plane: xpad[b][ph*58+pw][g 4] u64 ----
__global__ __launch_bounds__(256) void pack_x_kernel(const float* __restrict__ x, u64* __restrict__ xpad){
    int blk = blockIdx.x;              // b*58 + rp
    int rp = blk % 58, b = blk / 58;
    u64* rowbase = xpad + ((size_t)b*PADP + (size_t)rp*PADW)*4;
    int t = threadIdx.x;
    if (rp == 0 || rp == 57){          // zero pad rows (58*4 u64 = 464 ints)
        int* ip = (int*)rowbase;
        for (int j = t; j < PADW*4*2; j += 256) ip[j] = 0;
        return;
    }
    int h = rp - 1;
    __shared__ char lds[56][256];
    __shared__ int nib[4][64];
    int wave = t >> 6, l = t & 63;
    // phase 1: read x coalesced along w, write LDS transposed (bank-swizzled)
    for (int i = 0; i < 64; ++i){
        int c = wave*64 + i;
        if (l < 56){
            float v = x[((size_t)(b*CH + c))*POS + h*HWD + l];
            lds[l][c ^ ((l & 31) << 2)] = (v >= 0.f) ? (char)1 : (char)0;
        }
    }
    __syncthreads();
    // phase 2: lane l builds sign nibble for channels 4l..4l+3 of position p;
    // lanes 0..7 assemble the 4 u64 words (2 halves each) and store.
    for (int i = 0; i < 15; ++i){
        int p = wave + 4*i;
        if (p >= 58) break;
        int val = 0;
        if (p >= 1 && p <= 56){
            int w = p - 1;
            int swz = (w & 31) << 2;
            const char* lp = lds[w];
            int b0 = lp[(4*l + 0) ^ swz];
            int b1 = lp[(4*l + 1) ^ swz];
            int b2 = lp[(4*l + 2) ^ swz];
            int b3 = lp[(4*l + 3) ^ swz];
            val = b0 | (b1<<1) | (b2<<2) | (b3<<3);   // 4 sign bits in low nibble
        }
        nib[wave][l] = val;            // same-wave LDS: DS ops execute in issue order
        if (l < 8){
            int g4 = l & 3;            // u64 group
            int hi = l >> 2;           // which 32-bit half
            u64 part = 0;
            for (int k=0; k<8; ++k){   // 8 nibbles = 32 bits; channels g4*64+hi*32+4k..+3
                int lane_src = g4*16 + hi*8 + k;
                part |= (u64)(nib[wave][lane_src] & 0xF) << (4*k);
            }
            ((unsigned int*)(rowbase + (size_t)p*4 + g4))[hi] = (unsigned int)part;
        }
    }
}

// ---- conv: bit XOR-popcount. Block = (b, band of 4 rows, og of 8 o). 256 threads. ----
__global__ __launch_bounds__(256) void conv_kernel(
        const u64* __restrict__ xpad, const u64* __restrict__ wbit8,
        const int* __restrict__ ctap,
        short* __restrict__ y16, int* __restrict__ sumI, u64* __restrict__ sumQ){
    int blk = blockIdx.x;
    int og   = blk & 31;
    int band = (blk >> 5) % 14;
    int b    = blk / 448;
    int t = threadIdx.x;
    int h = band*4 + (t >> 6);
    int w = t & 63;
    bool vok = (w < 56);
    int wc = vok ? w : 55;

    const u64* xb = xpad + ((size_t)b*PADP + (size_t)(h+1)*PADW + (wc+1))*4;
    const u64* wb = wbit8 + (size_t)og*288;     // [tap][oo][g] -- block-uniform (s_load)

    int acc[8];
    #pragma unroll
    for (int i=0;i<8;i++) acc[i] = 0;

    #pragma unroll 1
    for (int tap=0; tap<9; ++tap){
        int dh = tap/3 - 1, dw = tap%3 - 1;
        const u64* xp = xb + (dh*PADW + dw)*4;
        u64 x0 = xp[0], x1 = xp[1], x2 = xp[2], x3 = xp[3];
        const u64* wt = wb + tap*32;
        #pragma unroll
        for (int oo=0; oo<8; ++oo){
            acc[oo] += __builtin_popcountll(x0 ^ wt[oo*4+0])
                     + __builtin_popcountll(x1 ^ wt[oo*4+1])
                     + __builtin_popcountll(x2 ^ wt[oo*4+2])
                     + __builtin_popcountll(x3 ^ wt[oo*4+3]);
        }
    }

    // ---- epilogue: padding correction, y store, stats via LDS transpose-reduce ----
    bool top=(h==0), bot=(h==55), left=(w==0), right=(w==55);
    int o0 = og*8;
    __shared__ int sbuf[8][264];
    __shared__ int qbuf[8][264];
    size_t ybase = ((size_t)(b*CH + o0)*HWD + h)*HWD + w;

    #pragma unroll
    for (int oo=0; oo<8; ++oo){
        const int* cp = ctap + (size_t)(o0+oo)*9;
        int corr = 0;
        if (top)   corr += cp[0]+cp[1]+cp[2];
        if (bot)   corr += cp[6]+cp[7]+cp[8];
        if (left)  corr += cp[0]+cp[3]+cp[6];
        if (right) corr += cp[2]+cp[5]+cp[8];
        if (top && left)   corr -= cp[0];
        if (top && right)  corr -= cp[2];
        if (bot && left)   corr -= cp[6];
        if (bot && right)  corr -= cp[8];
        int y = 2304 - 2*acc[oo] - corr;
        if (vok) y16[ybase + (size_t)oo*POS] = (short)y;
        sbuf[oo][t] = vok ? y : 0;
        qbuf[oo][t] = vok ? y*y : 0;
    }
    __syncthreads();
    {
        int oo = t >> 5, j = t & 31;
        int ss = 0, qq = 0;
        #pragma unroll
        for (int k=0; k<8; ++k){
            ss += sbuf[oo][j + 32*k];
            qq += qbuf[oo][j + 32*k];
        }
        #pragma unroll
        for (int off=1; off<32; off<<=1){
            ss += __shfl_xor(ss, off);
            qq += __shfl_xor(qq, off);  // block total <= 224*5.31e6 = 1.19e9, fits int32
        }
        if (j == 0){
            atomicAdd(&sumI[o0+oo], ss);
            atomicAdd(&sumQ[o0+oo], (u64)(unsigned)qq);
        }
    }
}

// ---- BN coefficients from exact integer sums ----
__global__ void bn_prep_kernel(const int* __restrict__ sumI, const u64* __restrict__ sumQ,
                               const float* __restrict__ gamma, const float* __restrict__ beta,
                               float* __restrict__ invA, float* __restrict__ shiftA){
    int o = threadIdx.x;
    const double N = (double)(BATCH*POS);
    double mean = (double)sumI[o] / N;
    double msq  = (double)sumQ[o] / N;
    double var  = msq - mean*mean;
    double inv  = (double)gamma[o] / sqrt(var + 1e-5);
    invA[o]   = (float)inv;
    shiftA[o] = (float)((double)beta[o] - mean*inv);
}

// ---- apply: out = y*inv + shift + x ----
__global__ void apply_kernel(const short* __restrict__ y16, const float* __restrict__ x,
                             const float* __restrict__ invA, const float* __restrict__ shiftA,
                             float* __restrict__ out){
    int t = blockIdx.x*blockDim.x + threadIdx.x;
    const int total8 = BATCH*CH*POS/8;
    if (t >= total8) return;
    size_t i = (size_t)t*8;
    int c = (t / (POS/8)) & 255;
    short8 yv = *(const short8*)(y16 + i);
    float4 x0 = *(const float4*)(x + i);
    float4 x1 = *(const float4*)(x + i + 4);
    float iv = invA[c], sh = shiftA[c];
    float4 o0, o1;
    o0.x = fmaf((float)yv[0], iv, sh) + x0.x;
    o0.y = fmaf((float)yv[1], iv, sh) + x0.y;
    o0.z = fmaf((float)yv[2], iv, sh) + x0.z;
    o0.w = fmaf((float)yv[3], iv, sh) + x0.w;
    o1.x = fmaf((float)yv[4], iv, sh) + x1.x;
    o1.y = fmaf((float)yv[5], iv, sh) + x1.y;
    o1.z = fmaf((float)yv[6], iv, sh) + x1.z;
    o1.w = fmaf((float)yv[7], iv, sh) + x1.w;
    *(float4*)(out + i)     = o0;
    *(float4*)(out + i + 4) = o1;
}

extern "C" void kernel_launch(void* const* d_in, const int* in_sizes, int n_in,
                              void* d_out, int out_size, void* d_ws, size_t ws_size,
                              hipStream_t stream) {
    const float* x     = (const float*)d_in[0];
    const float* W     = (const float*)d_in[1];
    const float* gamma = (const float*)d_in[2];
    const float* beta  = (const float*)d_in[3];
    float* out = (float*)d_out;

    char* ws = (char*)d_ws;
    // layout (bytes):
    //   y16    @ 0          : 32*256*3136*2 = 51,380,224
    //   xpad   @ 51,380,224 : 32*3364*4*8   =  3,444,736   (ends 54,824,960)
    //   wbit8  @ 54,824,960 : 32*9*8*4*8    =     73,728   (ends 54,898,688)
    //   ctap   @ 54,898,688 : 256*9*4       =      9,216   (ends 54,907,904)
    //   sumI   @ 54,907,904 : 1024 | sumQ @ +1024 : 2048 | invA, shiftA
    short* y16   = (short*)ws;
    u64*   xpad  = (u64*)(ws + 51380224);
    u64*   wbit8 = (u64*)(ws + 54824960);
    int*   ctap  = (int*)(ws + 54898688);
    int*   sumI  = (int*)(ws + 54907904);
    u64*   sumQ  = (u64*)(ws + 54908928);
    float* invA  = (float*)(ws + 54910976);
    float* shiftA= (float*)(ws + 54912000);

    hipMemsetAsync(sumI, 0, 3072, stream);

    pack_w_kernel<<<9, 256, 0, stream>>>(W, wbit8, ctap);
    pack_x_kernel<<<BATCH*58, 256, 0, stream>>>(x, xpad);
    conv_kernel<<<BATCH*32*14, 256, 0, stream>>>(xpad, wbit8, ctap, y16, sumI, sumQ);
    bn_prep_kernel<<<1, 256, 0, stream>>>(sumI, sumQ, gamma, beta, invA, shiftA);
    apply_kernel<<<(BATCH*CH*POS/8 + 255)/256, 256, 0, stream>>>(y16, x, invA, shiftA, out);
}

// Round 8
// 399.531 us; speedup vs baseline: 2.0574x; 1.0371x over previous
//
#include <hip/hip_runtime.h>
#include <stdint.h>

#define CH 256
#define HWD 56
#define POS 3136
#define BATCH 32
#define PADW 58
#define PADP (PADW*PADW)     // 3364

typedef unsigned long long u64;
typedef __attribute__((ext_vector_type(8))) short short8;

// ---- merged pack: blocks 0..35 pack W (+ctap), blocks 36.. pack x via ballot ----
__global__ __launch_bounds__(64) void pack_xw_kernel(
        const float* __restrict__ x, const float* __restrict__ W,
        u64* __restrict__ xpad, u64* __restrict__ wbit8, int* __restrict__ ctap){
    int blk = blockIdx.x;
    int l = threadIdx.x;            // 0..63
    if (blk < 36){
        // ---- weights: wbit8[og][tap][oo][g] + ctap[o*9+tap] ----
        int idx = blk*64 + l;       // o*9 + tap, 2304 total
        int o = idx / 9, tap = idx % 9;
        int kh = tap/3, kw = tap%3;
        int og = o >> 3, oo = o & 7;
        int totpop = 0;
        for (int g=0; g<4; g++){
            u64 bits = 0;
            for (int j=0; j<64; j++){
                float v = W[((size_t)(o*CH + g*64 + j)*3 + kh)*3 + kw];
                bits |= (u64)(v >= 0.f) << j;
            }
            wbit8[((size_t)(og*9 + tap)*8 + oo)*4 + g] = bits;
            totpop += __builtin_popcountll(bits);
        }
        ctap[idx] = 256 - 2*totpop;
        return;
    }
    // ---- input signs: chunk of 64 positions for one (b, channel-group g) ----
    int cid = blk - 36;             // (b*4 + g)*49 + chunk
    int chunk = cid % 49;
    int bg    = cid / 49;
    int g = bg & 3, b = bg >> 2;
    int p0 = chunk*64;
    const float* xp = x + ((size_t)(b*CH + g*64 + l))*POS + p0;  // lane = channel j
    u64 mine = 0;
    #pragma unroll
    for (int i=0; i<64; ++i){
        float v = xp[i];
        u64 ball = __ballot(v >= 0.f);   // bit j = sign of channel g*64+j at pos p0+i
        if (l == i) mine = ball;
    }
    int p = p0 + l;
    int h = p / HWD, w = p % HWD;
    xpad[((size_t)b*PADP + (size_t)(h+1)*PADW + (w+1))*4 + g] = mine;
}

// ---- conv: bit XOR-popcount (unchanged round-7 structure; at its VALU floor) ----
__global__ __launch_bounds__(256) void conv_kernel(
        const u64* __restrict__ xpad, const u64* __restrict__ wbit8,
        const int* __restrict__ ctap,
        short* __restrict__ y16, int* __restrict__ sumI, u64* __restrict__ sumQ){
    int blk = blockIdx.x;
    int og   = blk & 31;
    int band = (blk >> 5) % 14;
    int b    = blk / 448;
    int t = threadIdx.x;
    int h = band*4 + (t >> 6);
    int w = t & 63;
    bool vok = (w < 56);
    int wc = vok ? w : 55;

    const u64* xb = xpad + ((size_t)b*PADP + (size_t)(h+1)*PADW + (wc+1))*4;
    const u64* wb = wbit8 + (size_t)og*288;     // [tap][oo][g] -- block-uniform (s_load)

    int acc[8];
    #pragma unroll
    for (int i=0;i<8;i++) acc[i] = 0;

    #pragma unroll 1
    for (int tap=0; tap<9; ++tap){
        int dh = tap/3 - 1, dw = tap%3 - 1;
        const u64* xp = xb + (dh*PADW + dw)*4;
        u64 x0 = xp[0], x1 = xp[1], x2 = xp[2], x3 = xp[3];
        const u64* wt = wb + tap*32;
        #pragma unroll
        for (int oo=0; oo<8; ++oo){
            acc[oo] += __builtin_popcountll(x0 ^ wt[oo*4+0])
                     + __builtin_popcountll(x1 ^ wt[oo*4+1])
                     + __builtin_popcountll(x2 ^ wt[oo*4+2])
                     + __builtin_popcountll(x3 ^ wt[oo*4+3]);
        }
    }

    // ---- epilogue: padding correction, y store, stats via LDS transpose-reduce ----
    bool top=(h==0), bot=(h==55), left=(w==0), right=(w==55);
    int o0 = og*8;
    __shared__ int sbuf[8][264];
    __shared__ int qbuf[8][264];
    size_t ybase = ((size_t)(b*CH + o0)*HWD + h)*HWD + w;

    #pragma unroll
    for (int oo=0; oo<8; ++oo){
        const int* cp = ctap + (size_t)(o0+oo)*9;
        int corr = 0;
        if (top)   corr += cp[0]+cp[1]+cp[2];
        if (bot)   corr += cp[6]+cp[7]+cp[8];
        if (left)  corr += cp[0]+cp[3]+cp[6];
        if (right) corr += cp[2]+cp[5]+cp[8];
        if (top && left)   corr -= cp[0];
        if (top && right)  corr -= cp[2];
        if (bot && left)   corr -= cp[6];
        if (bot && right)  corr -= cp[8];
        int y = 2304 - 2*acc[oo] - corr;
        if (vok) y16[ybase + (size_t)oo*POS] = (short)y;
        sbuf[oo][t] = vok ? y : 0;
        qbuf[oo][t] = vok ? y*y : 0;
    }
    __syncthreads();
    {
        int oo = t >> 5, j = t & 31;
        int ss = 0, qq = 0;
        #pragma unroll
        for (int k=0; k<8; ++k){
            ss += sbuf[oo][j + 32*k];
            qq += qbuf[oo][j + 32*k];
        }
        #pragma unroll
        for (int off=1; off<32; off<<=1){
            ss += __shfl_xor(ss, off);
            qq += __shfl_xor(qq, off);  // block total <= 224*5.31e6 = 1.19e9, fits int32
        }
        if (j == 0){
            atomicAdd(&sumI[o0+oo], ss);
            atomicAdd(&sumQ[o0+oo], (u64)(unsigned)qq);
        }
    }
}

// ---- apply: out = y*inv + shift + x, BN coefficients computed inline ----
__global__ void apply_kernel(const short* __restrict__ y16, const float* __restrict__ x,
                             const int* __restrict__ sumI, const u64* __restrict__ sumQ,
                             const float* __restrict__ gamma, const float* __restrict__ beta,
                             float* __restrict__ out){
    int t = blockIdx.x*blockDim.x + threadIdx.x;
    const int total8 = BATCH*CH*POS/8;
    if (t >= total8) return;
    size_t i = (size_t)t*8;
    int c = (t / (POS/8)) & 255;

    const double N = (double)(BATCH*POS);
    double mean = (double)sumI[c] / N;
    double msq  = (double)sumQ[c] / N;
    double var  = msq - mean*mean;
    double inv  = (double)gamma[c] / sqrt(var + 1e-5);
    float iv = (float)inv;
    float sh = (float)((double)beta[c] - mean*inv);

    short8 yv = *(const short8*)(y16 + i);
    float4 x0 = *(const float4*)(x + i);
    float4 x1 = *(const float4*)(x + i + 4);
    float4 o0, o1;
    o0.x = fmaf((float)yv[0], iv, sh) + x0.x;
    o0.y = fmaf((float)yv[1], iv, sh) + x0.y;
    o0.z = fmaf((float)yv[2], iv, sh) + x0.z;
    o0.w = fmaf((float)yv[3], iv, sh) + x0.w;
    o1.x = fmaf((float)yv[4], iv, sh) + x1.x;
    o1.y = fmaf((float)yv[5], iv, sh) + x1.y;
    o1.z = fmaf((float)yv[6], iv, sh) + x1.z;
    o1.w = fmaf((float)yv[7], iv, sh) + x1.w;
    *(float4*)(out + i)     = o0;
    *(float4*)(out + i + 4) = o1;
}

extern "C" void kernel_launch(void* const* d_in, const int* in_sizes, int n_in,
                              void* d_out, int out_size, void* d_ws, size_t ws_size,
                              hipStream_t stream) {
    const float* x     = (const float*)d_in[0];
    const float* W     = (const float*)d_in[1];
    const float* gamma = (const float*)d_in[2];
    const float* beta  = (const float*)d_in[3];
    float* out = (float*)d_out;

    char* ws = (char*)d_ws;
    // layout (bytes):
    //   y16    @ 0          : 32*256*3136*2 = 51,380,224
    //   xpad   @ 51,380,224 : 32*3364*4*8   =  3,444,736   (ends 54,824,960)
    //   sumI   @ 54,824,960 : 1,024
    //   sumQ   @ 54,825,984 : 2,048                         (ends 54,828,032)
    //   wbit8  @ 54,828,032 : 73,728                        (ends 54,901,760)
    //   ctap   @ 54,901,760 : 9,216                         (ends 54,910,976)
    short* y16   = (short*)ws;
    u64*   xpad  = (u64*)(ws + 51380224);
    int*   sumI  = (int*)(ws + 54824960);
    u64*   sumQ  = (u64*)(ws + 54825984);
    u64*   wbit8 = (u64*)(ws + 54828032);
    int*   ctap  = (int*)(ws + 54901760);

    // one memset covers xpad (pad borders) + sumI + sumQ (contiguous)
    hipMemsetAsync(xpad, 0, 3444736 + 3072, stream);

    // merged pack: 36 W-blocks + 32*4*49 x-blocks (64 threads each)
    pack_xw_kernel<<<36 + BATCH*4*49, 64, 0, stream>>>(x, W, xpad, wbit8, ctap);
    conv_kernel<<<BATCH*32*14, 256, 0, stream>>>(xpad, wbit8, ctap, y16, sumI, sumQ);
    apply_kernel<<<(BATCH*CH*POS/8 + 255)/256, 256, 0, stream>>>(y16, x, sumI, sumQ, gamma, beta, out);
}

// Round 9
// 327.023 us; speedup vs baseline: 2.5135x; 1.2217x over previous
//
#include <hip/hip_runtime.h>
#include <stdint.h>

#define CH 256
#define HWD 56
#define POS 3136
#define BATCH 32
#define PP 3364          // 58*58 padded plane per batch
#define NCHUNK 51        // 64-slot output chunks per plane (covers rows 1..56)

typedef unsigned long long u64;
typedef __attribute__((ext_vector_type(4))) int  i32x4;
typedef __attribute__((ext_vector_type(16))) int i32x16;
typedef __attribute__((ext_vector_type(8))) short short8;

#define GLL16(gsrc, ldst) \
    __builtin_amdgcn_global_load_lds((const __attribute__((address_space(1))) void*)(gsrc), \
                                     (__attribute__((address_space(3))) void*)(ldst), 16, 0, 0)

// ---- pack: blocks 0..143 pack W fragment-ordered [tap][cc][o][16B];
//      blocks 144.. pack x signs channel-last, chunk-swizzled, zero-padded plane ----
__global__ __launch_bounds__(256) void pack_kernel(
        const float* __restrict__ x, const float* __restrict__ W,
        char* __restrict__ Xp, char* __restrict__ Wb2){
    int blk = blockIdx.x, t = threadIdx.x;
    if (blk < 144){
        int idx = blk*256 + t;          // (o*9+tap)*16 + cc ; 36864 total
        int cc = idx & 15;
        int ot = idx >> 4;
        int o = ot / 9, tap = ot % 9;
        char v16[16];
        #pragma unroll
        for (int j=0;j<16;j++){
            float v = W[(size_t)(o*CH + cc*16 + j)*9 + tap];
            v16[j] = (v >= 0.f) ? 1 : -1;
        }
        *(int4*)(Wb2 + ((size_t)(tap*16 + cc)*256 + o)*16) = *(int4*)v16;
        return;
    }
    int xb = blk - 144;                 // b*56 + h
    int h = xb % 56, b = xb / 56;
    __shared__ char lds[56][256];
    int wave = t >> 6, l = t & 63;
    for (int i = 0; i < 64; ++i){       // read x coalesced along w, transpose in LDS
        int c = wave*64 + i;
        if (l < 56){
            float v = x[((size_t)(b*CH + c))*POS + h*HWD + l];
            lds[l][c ^ ((l & 31) << 2)] = (v >= 0.f) ? (char)1 : (char)-1;
        }
    }
    __syncthreads();
    #pragma unroll
    for (int i = 0; i < 4; ++i){
        int idx = t + 256*i;            // 896 = 56 w * 16 cc
        if (idx < 896){
            int cc = idx & 15, w = idx >> 4;
            int swz = (w & 31) << 2;
            int4 val;
            val.x = *(const int*)&lds[w][(cc*16 + 0) ^ swz];
            val.y = *(const int*)&lds[w][(cc*16 + 4) ^ swz];
            val.z = *(const int*)&lds[w][(cc*16 + 8) ^ swz];
            val.w = *(const int*)&lds[w][(cc*16 +12) ^ swz];
            int n = b*PP + (h+1)*58 + (w+1);
            *(int4*)(Xp + (size_t)n*256 + ((cc ^ (n & 15)) << 4)) = val;
        }
    }
}

// ---- conv: 9 tap-GEMMs over one LDS-resident B tile. Block = 256o x 64n, 8 waves.
// Single barrier; A streamed from L2 to registers; B ds_read swizzle-free of conflicts. ----
__global__ __launch_bounds__(512, 4) void conv_kernel(
        const char* __restrict__ Xp, const char* __restrict__ Wb2,
        short* __restrict__ y16, int* __restrict__ sumI, u64* __restrict__ sumQ){
    __shared__ char BL[184*256];        // 47,104 B: slots n0-59 .. n0+124
    __shared__ int sS[256], sQ[256];
    int blk = blockIdx.x;
    int b = blk / NCHUNK, chunk = blk - b*NCHUNK;
    int n0 = b*PP + 58 + chunk*64;
    int t = threadIdx.x;
    int wave = t >> 6, l = t & 63;
    int half = l >> 5, l31 = l & 31;

    // stage B once (linear both sides; swizzle pre-baked in Xp)
    const char* src = Xp + (size_t)(n0 - 59)*256;
    #pragma unroll
    for (int i=0;i<6;++i){
        int idx = t + 512*i;
        if (idx < 2944) GLL16(src + (size_t)idx*16, BL + idx*16);
    }
    if (t < 256){ sS[t]=0; sQ[t]=0; }
    __syncthreads();                    // the only barrier before epilogue

    i32x16 acc[2];
    #pragma unroll
    for (int nt=0;nt<2;++nt)
        #pragma unroll
        for (int r=0;r<16;++r) acc[nt][r] = 0;

    int c0 = (n0 - 59) & 15;

    #pragma unroll 1
    for (int tap=0; tap<9; ++tap){
        int dh = tap/3 - 1, dw = tap%3 - 1;
        int off = dh*58 + dw;
        // A-fragments: o = wave*32 + l31, k = ks*32 + half*16 + 0..15
        const char* wt = Wb2 + (size_t)tap*65536 + (size_t)(half*256 + wave*32 + l31)*16;
        i32x4 afr[8];
        #pragma unroll
        for (int ks=0; ks<8; ++ks)
            afr[ks] = *(const i32x4*)(wt + ks*8192);
        #pragma unroll
        for (int nt=0; nt<2; ++nt){
            int s = 59 + nt*32 + l31 + off;     // B slot (0..181)
            int key = (s + c0) & 15;            // n&15 of the read position
            int sb = s << 8;
            #pragma unroll
            for (int ks=0; ks<8; ++ks){
                int kch = ks*2 + half;
                i32x4 bfr = *(const i32x4*)(BL + sb + ((kch ^ key) << 4));
                acc[nt] = __builtin_amdgcn_mfma_i32_32x32x32_i8(afr[ks], bfr, acc[nt], 0,0,0);
            }
        }
    }

    // epilogue: mask pad outputs, store y16, exact integer stats
    #pragma unroll
    for (int nt=0; nt<2; ++nt){
        unsigned nloc = 58 + chunk*64 + nt*32 + l31;   // plane-local padded index
        unsigned hq = nloc / 58;
        unsigned wq = nloc - hq*58;
        bool vok = (hq <= 56) && (wq >= 1) && (wq <= 56);
        size_t pbase = (size_t)(hq-1)*HWD + (wq-1);
        #pragma unroll
        for (int reg=0; reg<16; ++reg){
            int o = wave*32 + (reg&3) + 8*(reg>>2) + 4*half;
            int v = acc[nt][reg];
            if (vok) y16[(size_t)(b*CH + o)*POS + pbase] = (short)v;
            int s_ = vok ? v : 0;
            int q_ = vok ? v*v : 0;             // <= 64*2304^2/block/o, fits i32
            #pragma unroll
            for (int mk=1; mk<32; mk<<=1){
                s_ += __shfl_xor(s_, mk);
                q_ += __shfl_xor(q_, mk);
            }
            if (l31 == 0){
                atomicAdd(&sS[o], s_);
                atomicAdd(&sQ[o], q_);
            }
        }
    }
    __syncthreads();
    if (t < 256){
        atomicAdd(&sumI[t], sS[t]);
        atomicAdd(&sumQ[t], (u64)(unsigned)sQ[t]);
    }
}

// ---- apply: out = y*inv + shift + x, BN coefficients computed inline ----
__global__ void apply_kernel(const short* __restrict__ y16, const float* __restrict__ x,
                             const int* __restrict__ sumI, const u64* __restrict__ sumQ,
                             const float* __restrict__ gamma, const float* __restrict__ beta,
                             float* __restrict__ out){
    int t = blockIdx.x*blockDim.x + threadIdx.x;
    const int total8 = BATCH*CH*POS/8;
    if (t >= total8) return;
    size_t i = (size_t)t*8;
    int c = (t / (POS/8)) & 255;

    const double N = (double)(BATCH*POS);
    double mean = (double)sumI[c] / N;
    double msq  = (double)sumQ[c] / N;
    double var  = msq - mean*mean;
    double inv  = (double)gamma[c] / sqrt(var + 1e-5);
    float iv = (float)inv;
    float sh = (float)((double)beta[c] - mean*inv);

    short8 yv = *(const short8*)(y16 + i);
    float4 x0 = *(const float4*)(x + i);
    float4 x1 = *(const float4*)(x + i + 4);
    float4 o0, o1;
    o0.x = fmaf((float)yv[0], iv, sh) + x0.x;
    o0.y = fmaf((float)yv[1], iv, sh) + x0.y;
    o0.z = fmaf((float)yv[2], iv, sh) + x0.z;
    o0.w = fmaf((float)yv[3], iv, sh) + x0.w;
    o1.x = fmaf((float)yv[4], iv, sh) + x1.x;
    o1.y = fmaf((float)yv[5], iv, sh) + x1.y;
    o1.z = fmaf((float)yv[6], iv, sh) + x1.z;
    o1.w = fmaf((float)yv[7], iv, sh) + x1.w;
    *(float4*)(out + i)     = o0;
    *(float4*)(out + i + 4) = o1;
}

extern "C" void kernel_launch(void* const* d_in, const int* in_sizes, int n_in,
                              void* d_out, int out_size, void* d_ws, size_t ws_size,
                              hipStream_t stream) {
    const float* x     = (const float*)d_in[0];
    const float* W     = (const float*)d_in[1];
    const float* gamma = (const float*)d_in[2];
    const float* beta  = (const float*)d_in[3];
    float* out = (float*)d_out;

    // ws layout: y16 (51,380,224) | sumI (1024) | sumQ (2048) | Wb2 (73,728)
    char* ws = (char*)d_ws;
    short* y16   = (short*)ws;
    int*   sumI  = (int*)(ws + 51380224);
    u64*   sumQ  = (u64*)(ws + 51381248);
    char*  Wb2   = (char*)(ws + 51383296);

    // d_out doubles as scratch: [64-slot head guard | Xp 107648 slots | 64-slot tail guard]
    // (27.6 MB; dead before apply_kernel overwrites d_out)
    char* Xp = (char*)d_out + 64*256;

    hipMemsetAsync(d_out, 0, (size_t)(107648 + 128)*256, stream);  // pads + guards zero
    hipMemsetAsync(sumI, 0, 3072, stream);

    pack_kernel<<<144 + BATCH*HWD, 256, 0, stream>>>(x, W, Xp, Wb2);
    conv_kernel<<<BATCH*NCHUNK, 512, 0, stream>>>(Xp, Wb2, y16, sumI, sumQ);
    apply_kernel<<<(BATCH*CH*POS/8 + 255)/256, 256, 0, stream>>>(y16, x, sumI, sumQ, gamma, beta, out);
}

// Round 10
// 315.663 us; speedup vs baseline: 2.6040x; 1.0360x over previous
//
#include <hip/hip_runtime.h>
#include <stdint.h>

#define CH 256
#define HWD 56
#define POS 3136
#define BATCH 32
#define PP 3364          // 58*58 padded plane per batch
#define BN 128           // output slots per conv block
#define NCH 26           // chunks per plane (26*128 >= 3248 useful slots)

typedef unsigned long long u64;
typedef __attribute__((ext_vector_type(4))) int  i32x4;
typedef __attribute__((ext_vector_type(16))) int i32x16;
typedef __attribute__((ext_vector_type(8))) short short8;

#define GLL16(gsrc, ldst) \
    __builtin_amdgcn_global_load_lds((const __attribute__((address_space(1))) void*)(gsrc), \
                                     (__attribute__((address_space(3))) void*)(ldst), 16, 0, 0)

// ---- pack: blocks 0..143 pack W fragment-ordered [tap][cc][o][16B];
//      blocks 144.. pack x signs channel-last, chunk-swizzled, zero-padded plane ----
__global__ __launch_bounds__(256) void pack_kernel(
        const float* __restrict__ x, const float* __restrict__ W,
        char* __restrict__ Xp, char* __restrict__ Wb2){
    int blk = blockIdx.x, t = threadIdx.x;
    if (blk < 144){
        int idx = blk*256 + t;          // (o*9+tap)*16 + cc ; 36864 total
        int cc = idx & 15;
        int ot = idx >> 4;
        int o = ot / 9, tap = ot % 9;
        char v16[16];
        #pragma unroll
        for (int j=0;j<16;j++){
            float v = W[(size_t)(o*CH + cc*16 + j)*9 + tap];
            v16[j] = (v >= 0.f) ? 1 : -1;
        }
        *(int4*)(Wb2 + ((size_t)(tap*16 + cc)*256 + o)*16) = *(int4*)v16;
        return;
    }
    int xb = blk - 144;                 // b*56 + h
    int h = xb % 56, b = xb / 56;
    __shared__ char lds[56][256];
    // phase 1: vectorized float4 reads (14 per thread), transpose into LDS (bank-swizzled)
    #pragma unroll
    for (int i = 0; i < 14; ++i){
        int idx = i*256 + t;            // 3584 = 256 c * 14 wq
        int c = idx / 14, wq = idx - c*14;
        float4 v = *(const float4*)(x + ((size_t)(b*CH + c))*POS + h*HWD + wq*4);
        int w0 = wq*4;
        lds[w0+0][c ^ (((w0+0) & 31) << 2)] = (v.x >= 0.f) ? (char)1 : (char)-1;
        lds[w0+1][c ^ (((w0+1) & 31) << 2)] = (v.y >= 0.f) ? (char)1 : (char)-1;
        lds[w0+2][c ^ (((w0+2) & 31) << 2)] = (v.z >= 0.f) ? (char)1 : (char)-1;
        lds[w0+3][c ^ (((w0+3) & 31) << 2)] = (v.w >= 0.f) ? (char)1 : (char)-1;
    }
    __syncthreads();
    // phase 2: emit channel-last 16B chunks with pre-baked read-swizzle cc ^= (n&15)
    #pragma unroll
    for (int i = 0; i < 4; ++i){
        int idx = t + 256*i;            // 896 = 56 w * 16 cc
        if (idx < 896){
            int cc = idx & 15, w = idx >> 4;
            int swz = (w & 31) << 2;
            int4 val;
            val.x = *(const int*)&lds[w][(cc*16 + 0) ^ swz];
            val.y = *(const int*)&lds[w][(cc*16 + 4) ^ swz];
            val.z = *(const int*)&lds[w][(cc*16 + 8) ^ swz];
            val.w = *(const int*)&lds[w][(cc*16 +12) ^ swz];
            int n = b*PP + (h+1)*58 + (w+1);
            *(int4*)(Xp + (size_t)n*256 + ((cc ^ (n & 15)) << 4)) = val;
        }
    }
}

// ---- conv: 9 tap-GEMMs over one LDS B tile. Block = 256o x 128n, 8 waves = 4gm x 2gn.
// Per wave: 2 M-tiles x 2 N-tiles -> each B ds_read feeds 2 MFMAs. No inner barriers. ----
__global__ __launch_bounds__(512) void conv_kernel(
        const char* __restrict__ Xp, const char* __restrict__ Wb2,
        short* __restrict__ y16){
    __shared__ char BL[256*256];        // 65,536 B: slots n0-64 .. n0+191
    int blk = blockIdx.x;
    int b = blk / NCH, chunk = blk - b*NCH;
    int n0 = b*PP + 58 + chunk*BN;
    int t = threadIdx.x;
    int wave = t >> 6, l = t & 63;
    int gm = wave & 3, gn = wave >> 2;
    int half = l >> 5, l31 = l & 31;

    // stage B once (linear both sides; swizzle pre-baked in Xp)
    const char* src = Xp + (size_t)(n0 - 64)*256;
    #pragma unroll
    for (int i=0;i<8;++i){
        int idx = t + 512*i;            // 4096 x 16B = 64KB
        GLL16(src + (size_t)idx*16, BL + idx*16);
    }
    __syncthreads();                    // the only barrier

    i32x16 acc[2][2];
    #pragma unroll
    for (int m=0;m<2;++m)
        #pragma unroll
        for (int nt=0;nt<2;++nt)
            #pragma unroll
            for (int r=0;r<16;++r) acc[m][nt][r] = 0;

    int c0 = (n0 - 64) & 15;

    #pragma unroll 1
    for (int tap=0; tap<9; ++tap){
        int off = (tap/3 - 1)*58 + (tap%3 - 1);
        // A-fragments: o = gm*64 + m*32 + l31, k-chunk cc = 2ks + half
        const char* wt = Wb2 + (size_t)tap*65536 + (size_t)half*4096
                             + (size_t)(gm*64 + l31)*16;
        i32x4 afr[2][8];
        #pragma unroll
        for (int m=0;m<2;++m)
            #pragma unroll
            for (int ks=0; ks<8; ++ks)
                afr[m][ks] = *(const i32x4*)(wt + m*512 + ks*8192);
        #pragma unroll
        for (int nt=0; nt<2; ++nt){
            int s = 64 + gn*64 + nt*32 + l31 + off;   // B slot (5..250)
            int key = (s + c0) & 15;                  // n&15 of that position
            const char* bb = BL + (s << 8);
            #pragma unroll
            for (int ks=0; ks<8; ++ks){
                i32x4 bfr = *(const i32x4*)(bb + (((2*ks + half) ^ key) << 4));
                acc[0][nt] = __builtin_amdgcn_mfma_i32_32x32x32_i8(afr[0][ks], bfr, acc[0][nt], 0,0,0);
                acc[1][nt] = __builtin_amdgcn_mfma_i32_32x32x32_i8(afr[1][ks], bfr, acc[1][nt], 0,0,0);
            }
        }
    }

    // epilogue: mask pad outputs, store y16 (stats handled by stats_kernel)
    #pragma unroll
    for (int nt=0; nt<2; ++nt){
        unsigned nloc = 58 + chunk*BN + gn*64 + nt*32 + l31;   // plane-local padded idx
        unsigned hq = nloc / 58;
        unsigned wq = nloc - hq*58;
        bool vok = (hq <= 56) && (wq >= 1) && (wq <= 56);
        if (!vok) continue;
        size_t pbase = (size_t)(hq-1)*HWD + (wq-1);
        #pragma unroll
        for (int m=0;m<2;++m){
            #pragma unroll
            for (int reg=0; reg<16; ++reg){
                int o = gm*64 + m*32 + (reg&3) + 8*(reg>>2) + 4*half;
                y16[(size_t)(b*CH + o)*POS + pbase] = (short)acc[m][nt][reg];
            }
        }
    }
}

// ---- stats: block per channel o; stream y16, exact integer sums (no atomics) ----
__global__ __launch_bounds__(256) void stats_kernel(const short* __restrict__ y16,
                                                    int* __restrict__ sumI, u64* __restrict__ sumQ){
    int o = blockIdx.x, t = threadIdx.x;
    int s = 0; unsigned q = 0;          // per-thread: |s|<=392*2304, q<=392*2304^2<2^32
    for (int b=0; b<BATCH; ++b){
        const short8* yp = (const short8*)(y16 + ((size_t)(b*CH + o))*POS);
        for (int i=t; i<POS/8; i+=256){
            short8 v = yp[i];
            #pragma unroll
            for (int j=0;j<8;++j){ int vv = v[j]; s += vv; q += (unsigned)(vv*vv); }
        }
    }
    long long ls = s, lq = (long long)q;
    #pragma unroll
    for (int off=32; off; off>>=1){
        ls += __shfl_xor(ls, off);
        lq += __shfl_xor(lq, off);
    }
    __shared__ long long wsum[4], wsq[4];
    int wave = t >> 6, lane = t & 63;
    if (lane == 0){ wsum[wave] = ls; wsq[wave] = lq; }
    __syncthreads();
    if (t == 0){
        sumI[o] = (int)(wsum[0]+wsum[1]+wsum[2]+wsum[3]);
        sumQ[o] = (u64)(wsq[0]+wsq[1]+wsq[2]+wsq[3]);
    }
}

// ---- apply: out = y*inv + shift + x, BN coefficients computed inline ----
__global__ void apply_kernel(const short* __restrict__ y16, const float* __restrict__ x,
                             const int* __restrict__ sumI, const u64* __restrict__ sumQ,
                             const float* __restrict__ gamma, const float* __restrict__ beta,
                             float* __restrict__ out){
    int t = blockIdx.x*blockDim.x + threadIdx.x;
    const int total8 = BATCH*CH*POS/8;
    if (t >= total8) return;
    size_t i = (size_t)t*8;
    int c = (t / (POS/8)) & 255;

    const double N = (double)(BATCH*POS);
    double mean = (double)sumI[c] / N;
    double msq  = (double)sumQ[c] / N;
    double var  = msq - mean*mean;
    double inv  = (double)gamma[c] / sqrt(var + 1e-5);
    float iv = (float)inv;
    float sh = (float)((double)beta[c] - mean*inv);

    short8 yv = *(const short8*)(y16 + i);
    float4 x0 = *(const float4*)(x + i);
    float4 x1 = *(const float4*)(x + i + 4);
    float4 o0, o1;
    o0.x = fmaf((float)yv[0], iv, sh) + x0.x;
    o0.y = fmaf((float)yv[1], iv, sh) + x0.y;
    o0.z = fmaf((float)yv[2], iv, sh) + x0.z;
    o0.w = fmaf((float)yv[3], iv, sh) + x0.w;
    o1.x = fmaf((float)yv[4], iv, sh) + x1.x;
    o1.y = fmaf((float)yv[5], iv, sh) + x1.y;
    o1.z = fmaf((float)yv[6], iv, sh) + x1.z;
    o1.w = fmaf((float)yv[7], iv, sh) + x1.w;
    *(float4*)(out + i)     = o0;
    *(float4*)(out + i + 4) = o1;
}

extern "C" void kernel_launch(void* const* d_in, const int* in_sizes, int n_in,
                              void* d_out, int out_size, void* d_ws, size_t ws_size,
                              hipStream_t stream) {
    const float* x     = (const float*)d_in[0];
    const float* W     = (const float*)d_in[1];
    const float* gamma = (const float*)d_in[2];
    const float* beta  = (const float*)d_in[3];
    float* out = (float*)d_out;

    // ws layout: y16 (51,380,224) | Wb2 (589,824) | sumI (1024) | sumQ (2048)
    char* ws = (char*)d_ws;
    short* y16   = (short*)ws;
    char*  Wb2   = (char*)(ws + 51380224);
    int*   sumI  = (int*)(ws + 51970048);
    u64*   sumQ  = (u64*)(ws + 51971072);

    // d_out doubles as scratch: [64-slot head guard | Xp 107,648 slots | 128-slot tail guard]
    // (27.6 MB; dead before apply_kernel overwrites d_out)
    char* Xp = (char*)d_out + 64*256;

    hipMemsetAsync(d_out, 0, (size_t)(64 + 107648 + 128)*256, stream);  // pads + guards

    pack_kernel<<<144 + BATCH*HWD, 256, 0, stream>>>(x, W, Xp, Wb2);
    conv_kernel<<<BATCH*NCH, 512, 0, stream>>>(Xp, Wb2, y16);
    stats_kernel<<<CH, 256, 0, stream>>>(y16, sumI, sumQ);
    apply_kernel<<<(BATCH*CH*POS/8 + 255)/256, 256, 0, stream>>>(y16, x, sumI, sumQ, gamma, beta, out);
}

// Round 11
// 315.279 us; speedup vs baseline: 2.6072x; 1.0012x over previous
//
#include <hip/hip_runtime.h>
#include <stdint.h>

#define CH 256
#define HWD 56
#define POS 3136
#define BATCH 32
#define PP 3364          // 58*58 padded plane per batch
#define BN 128           // output slots per conv block
#define NCH 26           // chunks per plane (26*128 >= 3248 useful slots)

typedef unsigned long long u64;
typedef __attribute__((ext_vector_type(4))) int  i32x4;
typedef __attribute__((ext_vector_type(16))) int i32x16;
typedef __attribute__((ext_vector_type(8))) short short8;

#define GLL16(gsrc, ldst) \
    __builtin_amdgcn_global_load_lds((const __attribute__((address_space(1))) void*)(gsrc), \
                                     (__attribute__((address_space(3))) void*)(ldst), 16, 0, 0)

// ---- pack: blocks 0..143 -> W fragments; 144..175 -> pad rows; 176.. -> x signs ----
__global__ __launch_bounds__(256) void pack_kernel(
        const float* __restrict__ x, const float* __restrict__ W,
        char* __restrict__ Xp, char* __restrict__ Wb2){
    int blk = blockIdx.x, t = threadIdx.x;
    if (blk < 144){
        int idx = blk*256 + t;          // (o*9+tap)*16 + cc ; 36864 total
        int cc = idx & 15;
        int ot = idx >> 4;
        int o = ot / 9, tap = ot % 9;
        char v16[16];
        #pragma unroll
        for (int j=0;j<16;j++){
            float v = W[(size_t)(o*CH + cc*16 + j)*9 + tap];
            v16[j] = (v >= 0.f) ? 1 : -1;
        }
        *(int4*)(Wb2 + ((size_t)(tap*16 + cc)*256 + o)*16) = *(int4*)v16;
        return;
    }
    if (blk < 176){
        // zero pad rows 0 and 57 of plane b (58 slots each = 928 int4 per row)
        int b = blk - 144;
        int4* r0 = (int4*)(Xp + (size_t)(b*PP)*256);
        int4* r1 = (int4*)(Xp + (size_t)(b*PP + 57*58)*256);
        for (int j = t; j < 928; j += 256){ r0[j] = make_int4(0,0,0,0); r1[j] = make_int4(0,0,0,0); }
        return;
    }
    int xb = blk - 176;                 // b*56 + h
    int h = xb % 56, b = xb / 56;
    __shared__ char lds[56][256];
    // phase 1: vectorized float4 reads, transpose into LDS (bank-swizzled)
    #pragma unroll
    for (int i = 0; i < 14; ++i){
        int idx = i*256 + t;            // 3584 = 256 c * 14 wq
        int c = idx / 14, wq = idx - c*14;
        float4 v = *(const float4*)(x + ((size_t)(b*CH + c))*POS + h*HWD + wq*4);
        int w0 = wq*4;
        lds[w0+0][c ^ (((w0+0) & 31) << 2)] = (v.x >= 0.f) ? (char)1 : (char)-1;
        lds[w0+1][c ^ (((w0+1) & 31) << 2)] = (v.y >= 0.f) ? (char)1 : (char)-1;
        lds[w0+2][c ^ (((w0+2) & 31) << 2)] = (v.z >= 0.f) ? (char)1 : (char)-1;
        lds[w0+3][c ^ (((w0+3) & 31) << 2)] = (v.w >= 0.f) ? (char)1 : (char)-1;
    }
    __syncthreads();
    // edge-column pads of this row: slots (h+1)*58 + {0, 57}
    if (t < 32){
        int s = (h+1)*58 + ((t & 1) ? 57 : 0);
        ((int4*)(Xp + ((size_t)(b*PP + s))*256))[t >> 1] = make_int4(0,0,0,0);
    }
    // phase 2: emit channel-last 16B chunks with pre-baked read-swizzle cc ^= (n&15)
    #pragma unroll
    for (int i = 0; i < 4; ++i){
        int idx = t + 256*i;            // 896 = 56 w * 16 cc
        if (idx < 896){
            int cc = idx & 15, w = idx >> 4;
            int swz = (w & 31) << 2;
            int4 val;
            val.x = *(const int*)&lds[w][(cc*16 + 0) ^ swz];
            val.y = *(const int*)&lds[w][(cc*16 + 4) ^ swz];
            val.z = *(const int*)&lds[w][(cc*16 + 8) ^ swz];
            val.w = *(const int*)&lds[w][(cc*16 +12) ^ swz];
            int n = b*PP + (h+1)*58 + (w+1);
            *(int4*)(Xp + (size_t)n*256 + ((cc ^ (n & 15)) << 4)) = val;
        }
    }
}

// A-fragment load for pipeline step s (tap = s>>2, kh = s&3); 4 coalesced 16B L2 loads.
#define LOADA(s, r0, r1, r2, r3) { \
    const char* wp_ = Wb2 + (size_t)((((s)>>2)*16 + ((s)&3)*4 + half)*4096) + abase; \
    r0 = *(const i32x4*)(wp_);                 \
    r1 = *(const i32x4*)(wp_ + 512);           \
    r2 = *(const i32x4*)(wp_ + 8192);          \
    r3 = *(const i32x4*)(wp_ + 8192 + 512); }

// Compute step s: 4 B ds_reads + 8 MFMAs using fragments r0..r3.
#define COMP(s, r0, r1, r2, r3) { \
    int tap_ = (s) >> 2, kh_ = (s) & 3; \
    int off_ = (tap_/3 - 1)*58 + (tap_%3 - 1); \
    _Pragma("unroll") \
    for (int nt=0; nt<2; ++nt){ \
        int sl_ = 64 + gn*64 + nt*32 + l31 + off_; \
        int key_ = (sl_ + c0) & 15; \
        const char* bb_ = BL + (sl_ << 8); \
        i32x4 bf0_ = *(const i32x4*)(bb_ + (((kh_*4 + half) ^ key_) << 4)); \
        i32x4 bf1_ = *(const i32x4*)(bb_ + (((kh_*4 + 2 + half) ^ key_) << 4)); \
        acc[0][nt] = __builtin_amdgcn_mfma_i32_32x32x32_i8(r0, bf0_, acc[0][nt], 0,0,0); \
        acc[1][nt] = __builtin_amdgcn_mfma_i32_32x32x32_i8(r1, bf0_, acc[1][nt], 0,0,0); \
        acc[0][nt] = __builtin_amdgcn_mfma_i32_32x32x32_i8(r2, bf1_, acc[0][nt], 0,0,0); \
        acc[1][nt] = __builtin_amdgcn_mfma_i32_32x32x32_i8(r3, bf1_, acc[1][nt], 0,0,0); \
    } }

// ---- conv: 9 tap-GEMMs over one LDS B tile. Block = 256o x 128n, 8 waves = 4gm x 2gn.
// 36-step flattened K-loop, A double-buffered in registers (prefetch s+1 during s). ----
__global__ __launch_bounds__(512, 4) void conv_kernel(
        const char* __restrict__ Xp, const char* __restrict__ Wb2,
        short* __restrict__ y16){
    __shared__ char BL[256*256];        // 65,536 B: slots n0-64 .. n0+191
    int blk = blockIdx.x;
    int b = blk / NCH, chunk = blk - b*NCH;
    int n0 = b*PP + 58 + chunk*BN;
    int t = threadIdx.x;
    int wave = t >> 6, l = t & 63;
    int gm = wave & 3, gn = wave >> 2;
    int half = l >> 5, l31 = l & 31;

    // stage B once (linear both sides; swizzle pre-baked in Xp)
    const char* src = Xp + (size_t)(n0 - 64)*256;
    #pragma unroll
    for (int i=0;i<8;++i){
        int idx = t + 512*i;            // 4096 x 16B = 64KB
        GLL16(src + (size_t)idx*16, BL + idx*16);
    }
    __syncthreads();                    // the only barrier

    i32x16 acc[2][2];
    #pragma unroll
    for (int m=0;m<2;++m)
        #pragma unroll
        for (int nt=0;nt<2;++nt)
            #pragma unroll
            for (int r=0;r<16;++r) acc[m][nt][r] = 0;

    int c0 = (n0 - 64) & 15;
    size_t abase = (size_t)(gm*64 + l31)*16;

    i32x4 p0,p1,p2,p3, q0,q1,q2,q3;     // A double-buffer (named regs, static indexing)
    LOADA(0, p0,p1,p2,p3);
    #pragma unroll 1
    for (int s = 0; s < 36; s += 2){
        LOADA(s+1, q0,q1,q2,q3);
        COMP(s, p0,p1,p2,p3);
        if (s < 34) LOADA(s+2, p0,p1,p2,p3);
        COMP(s+1, q0,q1,q2,q3);
    }

    // epilogue: mask pad outputs, store y16
    #pragma unroll
    for (int nt=0; nt<2; ++nt){
        unsigned nloc = 58 + chunk*BN + gn*64 + nt*32 + l31;   // plane-local padded idx
        unsigned hq = nloc / 58;
        unsigned wq = nloc - hq*58;
        bool vok = (hq <= 56) && (wq >= 1) && (wq <= 56);
        if (!vok) continue;
        size_t pbase = (size_t)(hq-1)*HWD + (wq-1);
        #pragma unroll
        for (int m=0;m<2;++m){
            #pragma unroll
            for (int reg=0; reg<16; ++reg){
                int o = gm*64 + m*32 + (reg&3) + 8*(reg>>2) + 4*half;
                y16[(size_t)(b*CH + o)*POS + pbase] = (short)acc[m][nt][reg];
            }
        }
    }
}

// ---- stats: block per channel o; stream y16, exact integer sums (no atomics) ----
__global__ __launch_bounds__(256) void stats_kernel(const short* __restrict__ y16,
                                                    int* __restrict__ sumI, u64* __restrict__ sumQ){
    int o = blockIdx.x, t = threadIdx.x;
    int s = 0; unsigned q = 0;          // per-thread: |s|<=392*2304, q<=392*2304^2<2^32
    for (int b=0; b<BATCH; ++b){
        const short8* yp = (const short8*)(y16 + ((size_t)(b*CH + o))*POS);
        for (int i=t; i<POS/8; i+=256){
            short8 v = yp[i];
            #pragma unroll
            for (int j=0;j<8;++j){ int vv = v[j]; s += vv; q += (unsigned)(vv*vv); }
        }
    }
    long long ls = s, lq = (long long)q;
    #pragma unroll
    for (int off=32; off; off>>=1){
        ls += __shfl_xor(ls, off);
        lq += __shfl_xor(lq, off);
    }
    __shared__ long long wsum[4], wsq[4];
    int wave = t >> 6, lane = t & 63;
    if (lane == 0){ wsum[wave] = ls; wsq[wave] = lq; }
    __syncthreads();
    if (t == 0){
        sumI[o] = (int)(wsum[0]+wsum[1]+wsum[2]+wsum[3]);
        sumQ[o] = (u64)(wsq[0]+wsq[1]+wsq[2]+wsq[3]);
    }
}

// ---- apply: out = y*inv + shift + x, BN coefficients computed inline ----
__global__ void apply_kernel(const short* __restrict__ y16, const float* __restrict__ x,
                             const int* __restrict__ sumI, const u64* __restrict__ sumQ,
                             const float* __restrict__ gamma, const float* __restrict__ beta,
                             float* __restrict__ out){
    int t = blockIdx.x*blockDim.x + threadIdx.x;
    const int total8 = BATCH*CH*POS/8;
    if (t >= total8) return;
    size_t i = (size_t)t*8;
    int c = (t / (POS/8)) & 255;

    const double N = (double)(BATCH*POS);
    double mean = (double)sumI[c] / N;
    double msq  = (double)sumQ[c] / N;
    double var  = msq - mean*mean;
    double inv  = (double)gamma[c] / sqrt(var + 1e-5);
    float iv = (float)inv;
    float sh = (float)((double)beta[c] - mean*inv);

    short8 yv = *(const short8*)(y16 + i);
    float4 x0 = *(const float4*)(x + i);
    float4 x1 = *(const float4*)(x + i + 4);
    float4 o0, o1;
    o0.x = fmaf((float)yv[0], iv, sh) + x0.x;
    o0.y = fmaf((float)yv[1], iv, sh) + x0.y;
    o0.z = fmaf((float)yv[2], iv, sh) + x0.z;
    o0.w = fmaf((float)yv[3], iv, sh) + x0.w;
    o1.x = fmaf((float)yv[4], iv, sh) + x1.x;
    o1.y = fmaf((float)yv[5], iv, sh) + x1.y;
    o1.z = fmaf((float)yv[6], iv, sh) + x1.z;
    o1.w = fmaf((float)yv[7], iv, sh) + x1.w;
    *(float4*)(out + i)     = o0;
    *(float4*)(out + i + 4) = o1;
}

extern "C" void kernel_launch(void* const* d_in, const int* in_sizes, int n_in,
                              void* d_out, int out_size, void* d_ws, size_t ws_size,
                              hipStream_t stream) {
    const float* x     = (const float*)d_in[0];
    const float* W     = (const float*)d_in[1];
    const float* gamma = (const float*)d_in[2];
    const float* beta  = (const float*)d_in[3];
    float* out = (float*)d_out;

    // ws layout: y16 (51,380,224) | Wb2 (589,824) | sumI (1024) | sumQ (2048)
    char* ws = (char*)d_ws;
    short* y16   = (short*)ws;
    char*  Wb2   = (char*)(ws + 51380224);
    int*   sumI  = (int*)(ws + 51970048);
    u64*   sumQ  = (u64*)(ws + 51971072);

    // d_out doubles as scratch: [64-slot head guard | Xp 107,648 slots | 128-slot tail guard]
    // (27.6 MB; dead before apply_kernel overwrites d_out). Guards feed only masked
    // outputs, pads are zeroed by pack_kernel -> no memset needed.
    char* Xp = (char*)d_out + 64*256;

    pack_kernel<<<144 + 32 + BATCH*HWD, 256, 0, stream>>>(x, W, Xp, Wb2);
    conv_kernel<<<BATCH*NCH, 512, 0, stream>>>(Xp, Wb2, y16);
    stats_kernel<<<CH, 256, 0, stream>>>(y16, sumI, sumQ);
    apply_kernel<<<(BATCH*CH*POS/8 + 255)/256, 256, 0, stream>>>(y16, x, sumI, sumQ, gamma, beta, out);
}